// Round 3
// baseline (501.294 us; speedup 1.0000x reference)
//
#include <hip/hip_runtime.h>
#include <hip/hip_cooperative_groups.h>

namespace cg = cooperative_groups;

#define BB 2
#define SS 2048
#define DD 1024
#define HH 16
#define HDIM 64
#define MTOT 4096  // B*S
#define BKK 32
#define NBLK 768   // cooperative grid: 3 blocks/CU on 256 CUs
#define NTHR 196608  // NBLK*256

typedef unsigned short u16;
typedef __bf16 bf16_t;
typedef bf16_t bf16x8 __attribute__((ext_vector_type(8)));
typedef float floatx4 __attribute__((ext_vector_type(4)));
typedef float floatx16 __attribute__((ext_vector_type(16)));

__device__ __forceinline__ float bf2f(u16 u) {
  union { unsigned int i; float f; } x;
  x.i = ((unsigned int)u) << 16;
  return x.f;
}
// round-to-nearest-even f32 -> bf16 (finite inputs only)
__device__ __forceinline__ u16 f2bf(float f) {
  union { float f; unsigned int i; } x;
  x.f = f;
  unsigned int r = x.i + 0x7fffu + ((x.i >> 16) & 1u);
  return (u16)(r >> 16);
}

// async global->LDS, 16B per lane. LDS dest = wave-uniform base + lane*16.
__device__ __forceinline__ void gload16(const u16* g, u16* l) {
  __builtin_amdgcn_global_load_lds(
      (const __attribute__((address_space(1))) unsigned int*)g,
      (__attribute__((address_space(3))) unsigned int*)l, 16, 0, 0);
}

// ===================== fused cooperative kernel =====================
// phase 1: fp32->bf16 cast (grid-stride)
// phase 2: QKV gemm, round-0 structure (768 tile-blocks, 1:1 with grid)
// phase 3: m_partial (1024 vblocks)   phase 4: reduce (32768 f4)
// phase 5: ctx MFMA (512 vblocks)
// LDS is a 34816 B union: qkv 16384, m_partial 34816, ctx 9216.
__global__ __launch_bounds__(256, 3) void fused_kernel(
    const float* __restrict__ hs, const float* __restrict__ am,
    const float* __restrict__ wq, const float* __restrict__ bq,
    const float* __restrict__ wk, const float* __restrict__ bk,
    const float* __restrict__ wv, const float* __restrict__ bv,
    float* __restrict__ out,
    u16* __restrict__ hs_b, u16* __restrict__ wq_b,
    u16* __restrict__ wk_b, u16* __restrict__ wv_b,
    u16* __restrict__ q_b, u16* __restrict__ k_b, u16* __restrict__ v_b,
    float* __restrict__ mpart, u16* __restrict__ m_b) {
  cg::grid_group gg = cg::this_grid();
  __shared__ __align__(16) char smem[34816];
  const int tid = threadIdx.x;
  const int bid = blockIdx.x;          // 0..767
  const int gtid = bid * 256 + tid;    // 0..196607
  const int lane = tid & 63, wave = tid >> 6;
  const int l32 = lane & 31, khalf = lane >> 5;

  // ---------------- phase 1: cast ----------------
  for (int fid = gtid; fid < 1835008; fid += NTHR) {
    const float* src; u16* dst; int local;
    if (fid < 1048576) { src = hs; dst = hs_b; local = fid; }
    else if (fid < 1310720) { src = wq; dst = wq_b; local = fid - 1048576; }
    else if (fid < 1572864) { src = wk; dst = wk_b; local = fid - 1310720; }
    else { src = wv; dst = wv_b; local = fid - 1572864; }
    float4 v = reinterpret_cast<const float4*>(src)[local];
    ushort4 o;
    o.x = f2bf(v.x); o.y = f2bf(v.y); o.z = f2bf(v.z); o.w = f2bf(v.w);
    reinterpret_cast<ushort4*>(dst)[local] = o;
  }
  gg.sync();

  // ---------------- phase 2: QKV gemm (round-0 body) ----------------
  {
    u16* sA = reinterpret_cast<u16*>(smem);          // 128*32 u16 = 8192 B
    u16* sB = reinterpret_cast<u16*>(smem + 8192);   // 8192 B
    const int mt = bid / 24, ntall = bid % 24;
    const int seg = ntall >> 3, nt = ntall & 7;
    const u16* Wp = (seg == 0) ? wq_b : (seg == 1) ? wk_b : wv_b;
    const float* bp = (seg == 0) ? bq : (seg == 1) ? bk : bv;
    u16* Out = (seg == 0) ? q_b : (seg == 1) ? k_b : v_b;
    const int m0 = mt * 128, n0 = nt * 128;
    const int wm = (wave >> 1) * 64, wn = (wave & 1) * 64;
    const int srow0 = wave * 32 + (lane >> 2);
    const int scol = (lane & 3) * 8;
    floatx16 acc[2][2] = {};
    for (int k0 = 0; k0 < DD; k0 += BKK) {
#pragma unroll
      for (int c = 0; c < 2; ++c) {
        int r = srow0 + c * 16;
        gload16(hs_b + (size_t)(m0 + r) * DD + k0 + scol, sA + r * BKK + scol);
        gload16(Wp + (size_t)(n0 + r) * DD + k0 + scol, sB + r * BKK + scol);
      }
      __syncthreads();  // drains vmcnt(0) -> LDS tiles complete
#pragma unroll
      for (int kk = 0; kk < 2; ++kk) {
        bf16x8 af[2], bfr[2];
#pragma unroll
        for (int i = 0; i < 2; ++i)
          af[i] = *reinterpret_cast<const bf16x8*>(sA + (wm + i * 32 + l32) * BKK + kk * 16 + khalf * 8);
#pragma unroll
        for (int j = 0; j < 2; ++j)
          bfr[j] = *reinterpret_cast<const bf16x8*>(sB + (wn + j * 32 + l32) * BKK + kk * 16 + khalf * 8);
#pragma unroll
        for (int i = 0; i < 2; ++i)
#pragma unroll
          for (int j = 0; j < 2; ++j)
            acc[i][j] = __builtin_amdgcn_mfma_f32_32x32x16_bf16(af[i], bfr[j], acc[i][j], 0, 0, 0);
      }
      __syncthreads();
    }
    // epilogue: C/D layout col=lane&31, row=(reg&3)+8*(reg>>2)+4*(lane>>5)
#pragma unroll
    for (int j = 0; j < 2; ++j) {
      int col = n0 + wn + j * 32 + l32;
      float bias = bp[col];
#pragma unroll
      for (int i = 0; i < 2; ++i) {
#pragma unroll
        for (int reg = 0; reg < 16; ++reg) {
          int row = m0 + wm + i * 32 + (reg & 3) + 8 * (reg >> 2) + 4 * khalf;
          Out[(size_t)row * DD + col] = f2bf(acc[i][j][reg] + bias);
        }
      }
    }
  }
  gg.sync();

  // ---------------- phase 3: m_partial (X=V, Y=K -> M^T partials) ----------------
  {
    float* sX = reinterpret_cast<float*>(smem);           // 64*68 f = 17408 B
    float* sY = reinterpret_cast<float*>(smem + 17408);   // 17408 B
    const int e0 = (tid & 15) * 4, d0 = (tid >> 4) * 4;
    for (int vb = bid; vb < 1024; vb += NBLK) {
      const int chunk = vb >> 5, bh = vb & 31;
      const int b = bh >> 4, h = bh & 15;
      const int s0 = chunk * 64;
      if (vb != bid) __syncthreads();  // protect LDS before restage
      float acc[4][4] = {};
#pragma unroll
      for (int c = 0; c < 2; ++c) {
        int L = tid + c * 256;
        int srow = L >> 3;            // 0..63
        int col = (L & 7) * 8;        // 0..56
        size_t g = (size_t)(b * SS + s0 + srow) * DD + h * HDIM + col;
        uint4 xraw = *reinterpret_cast<const uint4*>(v_b + g);
        uint4 yraw = *reinterpret_cast<const uint4*>(k_b + g);
        float m = (am[b * SS + s0 + srow] >= 0.f) ? 1.f : 0.f;
        unsigned int xw[4] = {xraw.x, xraw.y, xraw.z, xraw.w};
        unsigned int yw[4] = {yraw.x, yraw.y, yraw.z, yraw.w};
#pragma unroll
        for (int q = 0; q < 4; ++q) {
          sX[srow * 68 + col + 2 * q]     = m * bf2f((u16)(xw[q] & 0xffffu));
          sX[srow * 68 + col + 2 * q + 1] = m * bf2f((u16)(xw[q] >> 16));
          sY[srow * 68 + col + 2 * q]     = bf2f((u16)(yw[q] & 0xffffu));
          sY[srow * 68 + col + 2 * q + 1] = bf2f((u16)(yw[q] >> 16));
        }
      }
      __syncthreads();
      for (int s = 0; s < 64; ++s) {
        float4 xx = *reinterpret_cast<const float4*>(&sX[s * 68 + e0]);
        float4 yy = *reinterpret_cast<const float4*>(&sY[s * 68 + d0]);
        float xa[4] = {xx.x, xx.y, xx.z, xx.w};
        float ya[4] = {yy.x, yy.y, yy.z, yy.w};
#pragma unroll
        for (int i = 0; i < 4; ++i)
#pragma unroll
          for (int j = 0; j < 4; ++j) acc[i][j] += xa[i] * ya[j];
      }
      float* outp = mpart + ((size_t)(chunk * 32 + bh)) * 4096;
#pragma unroll
      for (int i = 0; i < 4; ++i) {
        float4 o = {acc[i][0], acc[i][1], acc[i][2], acc[i][3]};
        *reinterpret_cast<float4*>(&outp[(e0 + i) * 64 + d0]) = o;
      }
    }
  }
  gg.sync();

  // ---------------- phase 4: reduce 32 partials -> M^T bf16 ----------------
  if (gtid < 32768) {
    const float* p = mpart + (size_t)gtid * 4;
    float4 s = {0.f, 0.f, 0.f, 0.f};
#pragma unroll
    for (int pc = 0; pc < 32; ++pc) {
      float4 v = *reinterpret_cast<const float4*>(p + (size_t)pc * 131072);
      s.x += v.x; s.y += v.y; s.z += v.z; s.w += v.w;
    }
    ushort4 o = {f2bf(s.x), f2bf(s.y), f2bf(s.z), f2bf(s.w)};
    *reinterpret_cast<ushort4*>(m_b + (size_t)gtid * 4) = o;
  }
  gg.sync();

  // ---------------- phase 5: ctx MFMA ----------------
  if (bid < 512) {
    u16* sMT = reinterpret_cast<u16*>(smem);  // 64*72 u16 = 9216 B
    const int mtile = bid & 31, h = bid >> 5;  // 512 = 32 x 16
    const int m0 = mtile * 128;
    const int b = m0 >> 11;
    const int bh = b * HH + h;
    const u16* mg = m_b + (size_t)bh * 4096;
#pragma unroll
    for (int c = 0; c < 2; ++c) {
      int L = c * 256 + tid;        // 512 x 8 elems = 64x64
      int d = L >> 3, e = (L & 7) * 8;
      *reinterpret_cast<uint4*>(&sMT[d * 72 + e]) =
          *reinterpret_cast<const uint4*>(&mg[d * 64 + e]);
    }
    __syncthreads();
    const int arow = m0 + wave * 32 + l32;
    const u16* qrow = q_b + (size_t)arow * DD + h * HDIM + khalf * 8;
    bf16x8 af[4], bfr[2][4];
#pragma unroll
    for (int k0 = 0; k0 < 4; ++k0) {
      af[k0] = *reinterpret_cast<const bf16x8*>(qrow + k0 * 16);
#pragma unroll
      for (int j = 0; j < 2; ++j)
        bfr[j][k0] = *reinterpret_cast<const bf16x8*>(
            &sMT[(j * 32 + l32) * 72 + k0 * 16 + khalf * 8]);
    }
    floatx16 acc[2] = {};
#pragma unroll
    for (int j = 0; j < 2; ++j)
#pragma unroll
      for (int k0 = 0; k0 < 4; ++k0)
        acc[j] = __builtin_amdgcn_mfma_f32_32x32x16_bf16(af[k0], bfr[j][k0], acc[j], 0, 0, 0);
#pragma unroll
    for (int j = 0; j < 2; ++j) {
      int col = h * HDIM + j * 32 + l32;
#pragma unroll
      for (int reg = 0; reg < 16; ++reg) {
        int r = m0 + wave * 32 + (reg & 3) + 8 * (reg >> 2) + 4 * khalf;
        out[(size_t)r * DD + col] = acc[j][reg];
      }
    }
  }
}

// ===================== fallback standalone kernels (non-cooperative path) =====================
__global__ __launch_bounds__(256) void cast_to_bf16(
    const float* __restrict__ hs, const float* __restrict__ wq,
    const float* __restrict__ wk, const float* __restrict__ wv,
    u16* __restrict__ hs_b, u16* __restrict__ wq_b,
    u16* __restrict__ wk_b, u16* __restrict__ wv_b) {
  int fid = blockIdx.x * 256 + threadIdx.x;
  const float* src;
  u16* dst;
  int local;
  if (fid < 1048576) { src = hs; dst = hs_b; local = fid; }
  else if (fid < 1310720) { src = wq; dst = wq_b; local = fid - 1048576; }
  else if (fid < 1572864) { src = wk; dst = wk_b; local = fid - 1310720; }
  else { src = wv; dst = wv_b; local = fid - 1572864; }
  float4 v = reinterpret_cast<const float4*>(src)[local];
  ushort4 o;
  o.x = f2bf(v.x); o.y = f2bf(v.y); o.z = f2bf(v.z); o.w = f2bf(v.w);
  reinterpret_cast<ushort4*>(dst)[local] = o;
}

__global__ __launch_bounds__(256) void qkv_gemm_kernel(
    const u16* __restrict__ A,
    const u16* __restrict__ Wq, const u16* __restrict__ Wk, const u16* __restrict__ Wv,
    const float* __restrict__ bq, const float* __restrict__ bk, const float* __restrict__ bv,
    u16* __restrict__ Qo, u16* __restrict__ Ko, u16* __restrict__ Vo) {
  __shared__ u16 sA[128 * BKK];
  __shared__ u16 sB[128 * BKK];
  const int mt = blockIdx.y, ntall = blockIdx.x;
  const int seg = ntall >> 3, nt = ntall & 7;
  const u16* Wp = (seg == 0) ? Wq : (seg == 1) ? Wk : Wv;
  const float* bp = (seg == 0) ? bq : (seg == 1) ? bk : bv;
  u16* Out = (seg == 0) ? Qo : (seg == 1) ? Ko : Vo;
  const int m0 = mt * 128, n0 = nt * 128;
  const int tid = threadIdx.x;
  const int lane = tid & 63, wave = tid >> 6;
  const int wm = (wave >> 1) * 64, wn = (wave & 1) * 64;
  const int l32 = lane & 31, khalf = lane >> 5;
  const int srow0 = wave * 32 + (lane >> 2);
  const int scol = (lane & 3) * 8;
  floatx16 acc[2][2] = {};
  for (int k0 = 0; k0 < DD; k0 += BKK) {
#pragma unroll
    for (int c = 0; c < 2; ++c) {
      int r = srow0 + c * 16;
      gload16(A + (size_t)(m0 + r) * DD + k0 + scol, sA + r * BKK + scol);
      gload16(Wp + (size_t)(n0 + r) * DD + k0 + scol, sB + r * BKK + scol);
    }
    __syncthreads();
#pragma unroll
    for (int kk = 0; kk < 2; ++kk) {
      bf16x8 af[2], bfr[2];
#pragma unroll
      for (int i = 0; i < 2; ++i)
        af[i] = *reinterpret_cast<const bf16x8*>(sA + (wm + i * 32 + l32) * BKK + kk * 16 + khalf * 8);
#pragma unroll
      for (int j = 0; j < 2; ++j)
        bfr[j] = *reinterpret_cast<const bf16x8*>(sB + (wn + j * 32 + l32) * BKK + kk * 16 + khalf * 8);
#pragma unroll
      for (int i = 0; i < 2; ++i)
#pragma unroll
        for (int j = 0; j < 2; ++j)
          acc[i][j] = __builtin_amdgcn_mfma_f32_32x32x16_bf16(af[i], bfr[j], acc[i][j], 0, 0, 0);
    }
    __syncthreads();
  }
#pragma unroll
  for (int j = 0; j < 2; ++j) {
    int col = n0 + wn + j * 32 + l32;
    float bias = bp[col];
#pragma unroll
    for (int i = 0; i < 2; ++i) {
#pragma unroll
      for (int reg = 0; reg < 16; ++reg) {
        int row = m0 + wm + i * 32 + (reg & 3) + 8 * (reg >> 2) + 4 * khalf;
        Out[(size_t)row * DD + col] = f2bf(acc[i][j][reg] + bias);
      }
    }
  }
}

__global__ __launch_bounds__(256) void m_partial_kernel(
    const u16* __restrict__ Xb, const u16* __restrict__ Yb,
    const float* __restrict__ am, float* __restrict__ mpart) {
  __shared__ float sX[64 * 68];
  __shared__ float sY[64 * 68];
  const int bh = blockIdx.y;
  const int b = bh >> 4, h = bh & 15;
  const int tid = threadIdx.x;
  const int e0 = (tid & 15) * 4, d0 = (tid >> 4) * 4;
  const int s0 = blockIdx.x * 64;
  float acc[4][4] = {};
#pragma unroll
  for (int c = 0; c < 2; ++c) {
    int L = tid + c * 256;
    int srow = L >> 3;
    int col = (L & 7) * 8;
    size_t g = (size_t)(b * SS + s0 + srow) * DD + h * HDIM + col;
    uint4 xraw = *reinterpret_cast<const uint4*>(Xb + g);
    uint4 yraw = *reinterpret_cast<const uint4*>(Yb + g);
    float m = (am[b * SS + s0 + srow] >= 0.f) ? 1.f : 0.f;
    unsigned int xw[4] = {xraw.x, xraw.y, xraw.z, xraw.w};
    unsigned int yw[4] = {yraw.x, yraw.y, yraw.z, yraw.w};
#pragma unroll
    for (int q = 0; q < 4; ++q) {
      sX[srow * 68 + col + 2 * q]     = m * bf2f((u16)(xw[q] & 0xffffu));
      sX[srow * 68 + col + 2 * q + 1] = m * bf2f((u16)(xw[q] >> 16));
      sY[srow * 68 + col + 2 * q]     = bf2f((u16)(yw[q] & 0xffffu));
      sY[srow * 68 + col + 2 * q + 1] = bf2f((u16)(yw[q] >> 16));
    }
  }
  __syncthreads();
  for (int s = 0; s < 64; ++s) {
    float4 xx = *reinterpret_cast<const float4*>(&sX[s * 68 + e0]);
    float4 yy = *reinterpret_cast<const float4*>(&sY[s * 68 + d0]);
    float xa[4] = {xx.x, xx.y, xx.z, xx.w};
    float ya[4] = {yy.x, yy.y, yy.z, yy.w};
#pragma unroll
    for (int i = 0; i < 4; ++i)
#pragma unroll
      for (int j = 0; j < 4; ++j) acc[i][j] += xa[i] * ya[j];
  }
  float* outp = mpart + ((size_t)(blockIdx.x * 32 + bh)) * 4096;
#pragma unroll
  for (int i = 0; i < 4; ++i) {
    float4 o = {acc[i][0], acc[i][1], acc[i][2], acc[i][3]};
    *reinterpret_cast<float4*>(&outp[(e0 + i) * 64 + d0]) = o;
  }
}

__global__ __launch_bounds__(128) void m_reduce_kernel(
    const float* __restrict__ mpart, u16* __restrict__ Mb) {
  int t = blockIdx.x * 128 + threadIdx.x;
  const float* p = mpart + (size_t)t * 4;
  float4 s = {0.f, 0.f, 0.f, 0.f};
#pragma unroll
  for (int pc = 0; pc < 32; ++pc) {
    float4 v = *reinterpret_cast<const float4*>(p + (size_t)pc * 131072);
    s.x += v.x; s.y += v.y; s.z += v.z; s.w += v.w;
  }
  ushort4 o = {f2bf(s.x), f2bf(s.y), f2bf(s.z), f2bf(s.w)};
  *reinterpret_cast<ushort4*>(Mb + (size_t)t * 4) = o;
}

__global__ __launch_bounds__(256) void ctx_kernel(
    const u16* __restrict__ Qb, const u16* __restrict__ Mb, float* __restrict__ Out) {
  __shared__ u16 sMT[64 * 72];
  const int m0 = blockIdx.x * 128;
  const int h = blockIdx.y;
  const int b = m0 >> 11;
  const int bh = b * HH + h;
  const int tid = threadIdx.x;
  const u16* mg = Mb + (size_t)bh * 4096;
#pragma unroll
  for (int c = 0; c < 2; ++c) {
    int L = c * 256 + tid;
    int d = L >> 3, e = (L & 7) * 8;
    *reinterpret_cast<uint4*>(&sMT[d * 72 + e]) =
        *reinterpret_cast<const uint4*>(&mg[d * 64 + e]);
  }
  __syncthreads();
  const int lane = tid & 63, wave = tid >> 6;
  const int l32 = lane & 31, khalf = lane >> 5;
  const int arow = m0 + wave * 32 + l32;
  const u16* qrow = Qb + (size_t)arow * DD + h * HDIM + khalf * 8;
  bf16x8 af[4], bfr[2][4];
#pragma unroll
  for (int k0 = 0; k0 < 4; ++k0) {
    af[k0] = *reinterpret_cast<const bf16x8*>(qrow + k0 * 16);
#pragma unroll
    for (int j = 0; j < 2; ++j)
      bfr[j][k0] = *reinterpret_cast<const bf16x8*>(
          &sMT[(j * 32 + l32) * 72 + k0 * 16 + khalf * 8]);
  }
  floatx16 acc[2] = {};
#pragma unroll
  for (int j = 0; j < 2; ++j)
#pragma unroll
    for (int k0 = 0; k0 < 4; ++k0)
      acc[j] = __builtin_amdgcn_mfma_f32_32x32x16_bf16(af[k0], bfr[j][k0], acc[j], 0, 0, 0);
#pragma unroll
  for (int j = 0; j < 2; ++j) {
    int col = h * HDIM + j * 32 + l32;
#pragma unroll
    for (int reg = 0; reg < 16; ++reg) {
      int r = m0 + wave * 32 + (reg & 3) + 8 * (reg >> 2) + 4 * khalf;
      Out[(size_t)r * DD + col] = acc[j][reg];
    }
  }
}

extern "C" void kernel_launch(void* const* d_in, const int* in_sizes, int n_in,
                              void* d_out, int out_size, void* d_ws, size_t ws_size,
                              hipStream_t stream) {
  const float* hs = (const float*)d_in[0];
  const float* am = (const float*)d_in[1];
  const float* wq = (const float*)d_in[2];
  const float* bq = (const float*)d_in[3];
  const float* wk = (const float*)d_in[4];
  const float* bk = (const float*)d_in[5];
  const float* wv = (const float*)d_in[6];
  const float* bv = (const float*)d_in[7];
  float* out = (float*)d_out;
  char* ws = (char*)d_ws;

  // workspace layout (bytes), all 16B-aligned; total ~54.5 MB
  u16* hs_b = (u16*)(ws);                  // 8 MiB  [4096,1024] bf16
  u16* wq_b = (u16*)(ws + 8388608);        // 2 MiB
  u16* wk_b = (u16*)(ws + 10485760);       // 2 MiB
  u16* wv_b = (u16*)(ws + 12582912);       // 2 MiB
  u16* q_b  = (u16*)(ws + 14680064);       // 8 MiB
  u16* k_b  = (u16*)(ws + 23068672);       // 8 MiB
  u16* v_b  = (u16*)(ws + 31457280);       // 8 MiB
  float* mpart = (float*)(ws + 39845888);  // 16 MiB [32 pc][32 bh][64][64] f32 (M^T partials)
  u16* m_b  = (u16*)(ws + 56623104);       // 256 KiB [32 bh][64*64] bf16 (M^T)

  void* args[] = {(void*)&hs, (void*)&am, (void*)&wq, (void*)&bq,
                  (void*)&wk, (void*)&bk, (void*)&wv, (void*)&bv,
                  (void*)&out, (void*)&hs_b, (void*)&wq_b, (void*)&wk_b,
                  (void*)&wv_b, (void*)&q_b, (void*)&k_b, (void*)&v_b,
                  (void*)&mpart, (void*)&m_b};
  hipError_t err = hipLaunchCooperativeKernel((const void*)fused_kernel,
                                              dim3(NBLK), dim3(256), args, 0, stream);
  if (err != hipSuccess) {
    // fallback: 5-dispatch non-cooperative path (round-0 qkv structure)
    cast_to_bf16<<<7168, 256, 0, stream>>>(hs, wq, wk, wv, hs_b, wq_b, wk_b, wv_b);
    qkv_gemm_kernel<<<dim3(24, 32), 256, 0, stream>>>(hs_b, wq_b, wk_b, wv_b,
                                                      bq, bk, bv, q_b, k_b, v_b);
    m_partial_kernel<<<dim3(32, 32), 256, 0, stream>>>(v_b, k_b, am, mpart);
    m_reduce_kernel<<<256, 128, 0, stream>>>(mpart, m_b);
    ctx_kernel<<<dim3(32, 16), 256, 0, stream>>>(q_b, m_b, out);
  }
}

// Round 4
// 145.136 us; speedup vs baseline: 3.4540x; 3.4540x over previous
//
#include <hip/hip_runtime.h>

#define BB 2
#define SS 2048
#define DD 1024
#define HH 16
#define HDIM 64
#define MTOT 4096  // B*S

typedef unsigned short u16;
typedef __bf16 bf16_t;
typedef bf16_t bf16x8 __attribute__((ext_vector_type(8)));
typedef float floatx4 __attribute__((ext_vector_type(4)));

__device__ __forceinline__ float bf2f(u16 u) {
  union { unsigned int i; float f; } x;
  x.i = ((unsigned int)u) << 16;
  return x.f;
}
// round-to-nearest-even f32 -> bf16 (finite inputs only)
__device__ __forceinline__ u16 f2bf(float f) {
  union { float f; unsigned int i; } x;
  x.f = f;
  unsigned int r = x.i + 0x7fffu + ((x.i >> 16) & 1u);
  return (u16)(r >> 16);
}

// async global->LDS, 16B per lane. LDS dest = wave-uniform base + lane*16.
__device__ __forceinline__ void gload16(const u16* g, u16* l) {
  __builtin_amdgcn_global_load_lds(
      (const __attribute__((address_space(1))) unsigned int*)g,
      (__attribute__((address_space(3))) unsigned int*)l, 16, 0, 0);
}

// ---------------- kernel 1: fp32 -> bf16 cast of hs, Wq, Wk, Wv ----------------
__global__ __launch_bounds__(256) void cast_to_bf16(
    const float* __restrict__ hs, const float* __restrict__ wq,
    const float* __restrict__ wk, const float* __restrict__ wv,
    u16* __restrict__ hs_b, u16* __restrict__ wq_b,
    u16* __restrict__ wk_b, u16* __restrict__ wv_b) {
  int fid = blockIdx.x * 256 + threadIdx.x;  // 0 .. 1835007
  const float* src;
  u16* dst;
  int local;
  if (fid < 1048576) { src = hs; dst = hs_b; local = fid; }
  else if (fid < 1310720) { src = wq; dst = wq_b; local = fid - 1048576; }
  else if (fid < 1572864) { src = wk; dst = wk_b; local = fid - 1310720; }
  else { src = wv; dst = wv_b; local = fid - 1572864; }
  float4 v = reinterpret_cast<const float4*>(src)[local];
  ushort4 o;
  o.x = f2bf(v.x); o.y = f2bf(v.y); o.z = f2bf(v.z); o.w = f2bf(v.w);
  reinterpret_cast<ushort4*>(dst)[local] = o;
}

// ---------------- kernel 2: fused QKV projection, 256x256 tile deep-pipelined ----------------
// C[m,n] = sum_k A[m,k]*W[n,k] + bias[n].  A [4096,1024] bf16, W [1024,1024] bf16 (B^T layout).
// 192 blocks (3 segs x 16 mt x 4 nt), 512 thr = 8 waves (2M x 4N), wave output 128x64.
// mfma_f32_16x16x32_bf16, acc[8][4] f32x4. BK=64, LDS 2 x (A 32K + B 32K) = 128 KiB dbuf.
// Pipeline: full next-tile stage issued at phase 0 of current tile; vmcnt(0) drain only at
// end-of-tile (raw s_barrier everywhere -> no compiler vmcnt(0)-before-barrier drains).
// Swizzle (rule #21 both-sides): LDS dest linear, global source col slot^(row&7), reads re-XOR.
__global__ __launch_bounds__(512, 2) void qkv_gemm_8ph(
    const u16* __restrict__ A,
    const u16* __restrict__ Wq, const u16* __restrict__ Wk, const u16* __restrict__ Wv,
    const float* __restrict__ bq, const float* __restrict__ bk, const float* __restrict__ bv,
    u16* __restrict__ Qo, u16* __restrict__ Ko, u16* __restrict__ Vo) {
  __shared__ u16 lds[2][2][16384];  // [buf][A|B][256 rows * 64 bf16] = 32 KiB each
  // bijective XCD swizzle: 192 = 8 XCDs x 24 consecutive ids
  const int raw = blockIdx.x;
  const int id = (raw & 7) * 24 + (raw >> 3);
  const int seg = id >> 6, rem = id & 63;
  const int mt = rem >> 2, nt = rem & 3;
  const u16* Wp = (seg == 0) ? Wq : (seg == 1) ? Wk : Wv;
  const float* bp = (seg == 0) ? bq : (seg == 1) ? bk : bv;
  u16* Out = (seg == 0) ? Qo : (seg == 1) ? Ko : Vo;
  const int m0 = mt * 256, n0 = nt * 256;
  const int tid = threadIdx.x;
  const int lane = tid & 63, wave = tid >> 6;
  const int l15 = lane & 15, kh = lane >> 4;   // frag: row=l15, k=kh*8+j
  const int wrow0 = (wave >> 2) * 128;         // wave M origin in tile
  const int wcol0 = (wave & 3) * 64;           // wave N origin in tile

  // staging coords: 4 chunks x 512 thr cover 2048 (row,slot) 16B-cells per matrix
  int srow[4], sgc[4], soff[4];
#pragma unroll
  for (int c = 0; c < 4; ++c) {
    int L = c * 512 + tid;
    srow[c] = L >> 3;                       // 0..255
    sgc[c] = ((L & 7) ^ (srow[c] & 7)) << 3;  // pre-swizzled global col (elements)
    soff[c] = L << 3;                       // L*16 bytes = L*8 u16, lane-linear LDS
  }

#define STAGE(buf, kbase)                                                    \
  {                                                                          \
    _Pragma("unroll") for (int c = 0; c < 4; ++c) {                          \
      gload16(A + (size_t)(m0 + srow[c]) * DD + (kbase) + sgc[c],            \
              &lds[buf][0][soff[c]]);                                        \
      gload16(Wp + (size_t)(n0 + srow[c]) * DD + (kbase) + sgc[c],           \
              &lds[buf][1][soff[c]]);                                        \
    }                                                                        \
  }

  floatx4 acc[8][4] = {};
  STAGE(0, 0);
  asm volatile("s_waitcnt vmcnt(0)" ::: "memory");
  asm volatile("s_barrier" ::: "memory");

  for (int t = 0; t < 16; ++t) {
    const int cur = t & 1;
    const char* pA = (const char*)lds[cur][0];
    const char* pB = (const char*)lds[cur][1];
    bf16x8 b[4];
#pragma unroll
    for (int p = 0; p < 4; ++p) {
      const int mg = p & 1, ks = p >> 1;  // phase = (m-half, k-slice)
      if (p == 0 && t < 15) STAGE(cur ^ 1, (t + 1) * 64);  // issue-early prefetch
      const int sw = (((ks * 4 + kh) ^ (l15 & 7)) << 4);   // swizzled 16B slot
      bf16x8 a[4];
#pragma unroll
      for (int i = 0; i < 4; ++i) {
        int ra = wrow0 + (mg * 4 + i) * 16 + l15;
        a[i] = *reinterpret_cast<const bf16x8*>(pA + ra * 128 + sw);
      }
      if (mg == 0) {  // B frags reused across the two m-half phases of this k-slice
#pragma unroll
        for (int nf = 0; nf < 4; ++nf) {
          int rb = wcol0 + nf * 16 + l15;
          b[nf] = *reinterpret_cast<const bf16x8*>(pB + rb * 128 + sw);
        }
      }
      asm volatile("s_barrier" ::: "memory");  // raw: no vmcnt drain, phase-locks waves
      __builtin_amdgcn_s_setprio(1);
#pragma unroll
      for (int i = 0; i < 4; ++i)
#pragma unroll
        for (int nf = 0; nf < 4; ++nf)
          acc[mg * 4 + i][nf] = __builtin_amdgcn_mfma_f32_16x16x32_bf16(
              a[i], b[nf], acc[mg * 4 + i][nf], 0, 0, 0);
      __builtin_amdgcn_s_setprio(0);
    }
    // end of tile: next-tile loads (issued ~4 phases ago) must land; reads of cur retired.
    asm volatile("s_waitcnt vmcnt(0)" ::: "memory");
    asm volatile("s_barrier" ::: "memory");
  }
#undef STAGE

  // epilogue: C/D 16x16 layout col=lane&15, row=(lane>>4)*4+j
#pragma unroll
  for (int nf = 0; nf < 4; ++nf) {
    int col = n0 + wcol0 + nf * 16 + l15;
    float bias = bp[col];
#pragma unroll
    for (int mf = 0; mf < 8; ++mf) {
#pragma unroll
      for (int j = 0; j < 4; ++j) {
        int row = m0 + wrow0 + mf * 16 + kh * 4 + j;
        Out[(size_t)row * DD + col] = f2bf(acc[mf][nf][j] + bias);
      }
    }
  }
}

// ---------------- kernel 3: mpart[pc][bh][d][e] = sum_{s in chunk pc} mask[s]*V[s,d]*K[s,e] ----------------
// grid (32 chunks of 64 s-rows, 32 bh) = 1024 blocks -> 4 blocks/CU.
__global__ __launch_bounds__(256) void m_partial_kernel(
    const u16* __restrict__ Xb, const u16* __restrict__ Yb,
    const float* __restrict__ am, float* __restrict__ mpart) {
  __shared__ float sX[64 * 68];
  __shared__ float sY[64 * 68];
  const int bh = blockIdx.y;     // 0..31
  const int b = bh >> 4, h = bh & 15;
  const int tid = threadIdx.x;
  const int e0 = (tid & 15) * 4, d0 = (tid >> 4) * 4;
  const int s0 = blockIdx.x * 64;
  float acc[4][4] = {};
#pragma unroll
  for (int c = 0; c < 2; ++c) {
    int L = tid + c * 256;
    int srow = L >> 3;            // 0..63
    int col = (L & 7) * 8;        // 0..56
    size_t g = (size_t)(b * SS + s0 + srow) * DD + h * HDIM + col;
    uint4 xraw = *reinterpret_cast<const uint4*>(Xb + g);
    uint4 yraw = *reinterpret_cast<const uint4*>(Yb + g);
    float m = (am[b * SS + s0 + srow] >= 0.f) ? 1.f : 0.f;
    unsigned int xw[4] = {xraw.x, xraw.y, xraw.z, xraw.w};
    unsigned int yw[4] = {yraw.x, yraw.y, yraw.z, yraw.w};
#pragma unroll
    for (int q = 0; q < 4; ++q) {
      sX[srow * 68 + col + 2 * q]     = m * bf2f((u16)(xw[q] & 0xffffu));
      sX[srow * 68 + col + 2 * q + 1] = m * bf2f((u16)(xw[q] >> 16));
      sY[srow * 68 + col + 2 * q]     = bf2f((u16)(yw[q] & 0xffffu));
      sY[srow * 68 + col + 2 * q + 1] = bf2f((u16)(yw[q] >> 16));
    }
  }
  __syncthreads();
  for (int s = 0; s < 64; ++s) {
    float4 xx = *reinterpret_cast<const float4*>(&sX[s * 68 + e0]);
    float4 yy = *reinterpret_cast<const float4*>(&sY[s * 68 + d0]);
    float xa[4] = {xx.x, xx.y, xx.z, xx.w};
    float ya[4] = {yy.x, yy.y, yy.z, yy.w};
#pragma unroll
    for (int i = 0; i < 4; ++i)
#pragma unroll
      for (int j = 0; j < 4; ++j) acc[i][j] += xa[i] * ya[j];
  }
  float* outp = mpart + ((size_t)(blockIdx.x * 32 + bh)) * 4096;
#pragma unroll
  for (int i = 0; i < 4; ++i) {
    float4 o = {acc[i][0], acc[i][1], acc[i][2], acc[i][3]};
    *reinterpret_cast<float4*>(&outp[(e0 + i) * 64 + d0]) = o;
  }
}

// ---------------- kernel 4: reduce 32 partials -> M^T bf16 [32 bh][64*64] ----------------
__global__ __launch_bounds__(128) void m_reduce_kernel(
    const float* __restrict__ mpart, u16* __restrict__ Mb) {
  int t = blockIdx.x * 128 + threadIdx.x;  // 0..32767
  const float* p = mpart + (size_t)t * 4;
  float4 s = {0.f, 0.f, 0.f, 0.f};
#pragma unroll
  for (int pc = 0; pc < 32; ++pc) {
    float4 v = *reinterpret_cast<const float4*>(p + (size_t)pc * 131072);
    s.x += v.x; s.y += v.y; s.z += v.z; s.w += v.w;
  }
  ushort4 o = {f2bf(s.x), f2bf(s.y), f2bf(s.z), f2bf(s.w)};
  *reinterpret_cast<ushort4*>(Mb + (size_t)t * 4) = o;
}

// ---------------- kernel 5: ctx[m, h*64+d] = sum_e Q[m, h*64+e] * M[e,d]  (MFMA) ----------------
__global__ __launch_bounds__(256) void ctx_kernel(
    const u16* __restrict__ Qb, const u16* __restrict__ Mb, float* __restrict__ Out) {
  __shared__ u16 sMT[64 * 72];
  const int m0 = blockIdx.x * 128;
  const int h = blockIdx.y;
  const int b = m0 >> 11;         // 128-row tiles never cross the batch boundary
  const int bh = b * HH + h;
  const int tid = threadIdx.x;
  const u16* mg = Mb + (size_t)bh * 4096;
#pragma unroll
  for (int c = 0; c < 2; ++c) {
    int L = c * 256 + tid;        // 512 x 8 elems = 64x64
    int d = L >> 3, e = (L & 7) * 8;
    *reinterpret_cast<uint4*>(&sMT[d * 72 + e]) =
        *reinterpret_cast<const uint4*>(&mg[d * 64 + e]);
  }
  __syncthreads();
  const int lane = tid & 63, wave = tid >> 6;
  const int l32 = lane & 31, khalf = lane >> 5;
  const int arow = m0 + wave * 32 + l32;
  const u16* qrow = Qb + (size_t)arow * DD + h * HDIM + khalf * 8;
  typedef float floatx16 __attribute__((ext_vector_type(16)));
  bf16x8 af[4], bfr[2][4];
#pragma unroll
  for (int k0 = 0; k0 < 4; ++k0) {
    af[k0] = *reinterpret_cast<const bf16x8*>(qrow + k0 * 16);
#pragma unroll
    for (int j = 0; j < 2; ++j)
      bfr[j][k0] = *reinterpret_cast<const bf16x8*>(
          &sMT[(j * 32 + l32) * 72 + k0 * 16 + khalf * 8]);
  }
  floatx16 acc[2] = {};
#pragma unroll
  for (int j = 0; j < 2; ++j)
#pragma unroll
    for (int k0 = 0; k0 < 4; ++k0)
      acc[j] = __builtin_amdgcn_mfma_f32_32x32x16_bf16(af[k0], bfr[j][k0], acc[j], 0, 0, 0);
  // C/D layout: col = lane&31, row = (reg&3)+8*(reg>>2)+4*khalf
#pragma unroll
  for (int j = 0; j < 2; ++j) {
    int col = h * HDIM + j * 32 + l32;
#pragma unroll
    for (int reg = 0; reg < 16; ++reg) {
      int r = m0 + wave * 32 + (reg & 3) + 8 * (reg >> 2) + 4 * khalf;
      Out[(size_t)r * DD + col] = acc[j][reg];
    }
  }
}

extern "C" void kernel_launch(void* const* d_in, const int* in_sizes, int n_in,
                              void* d_out, int out_size, void* d_ws, size_t ws_size,
                              hipStream_t stream) {
  const float* hs = (const float*)d_in[0];
  const float* am = (const float*)d_in[1];
  const float* wq = (const float*)d_in[2];
  const float* bq = (const float*)d_in[3];
  const float* wk = (const float*)d_in[4];
  const float* bk = (const float*)d_in[5];
  const float* wv = (const float*)d_in[6];
  const float* bv = (const float*)d_in[7];
  float* out = (float*)d_out;
  char* ws = (char*)d_ws;

  // workspace layout (bytes), all 16B-aligned; total ~54.5 MB
  u16* hs_b = (u16*)(ws);                  // 8 MiB  [4096,1024] bf16
  u16* wq_b = (u16*)(ws + 8388608);        // 2 MiB
  u16* wk_b = (u16*)(ws + 10485760);       // 2 MiB
  u16* wv_b = (u16*)(ws + 12582912);       // 2 MiB
  u16* q_b  = (u16*)(ws + 14680064);       // 8 MiB
  u16* k_b  = (u16*)(ws + 23068672);       // 8 MiB
  u16* v_b  = (u16*)(ws + 31457280);       // 8 MiB
  float* mpart = (float*)(ws + 39845888);  // 16 MiB [32 pc][32 bh][64][64] f32 (M^T partials)
  u16* m_b  = (u16*)(ws + 56623104);       // 256 KiB [32 bh][64*64] bf16 (M^T)

  cast_to_bf16<<<7168, 256, 0, stream>>>(hs, wq, wk, wv, hs_b, wq_b, wk_b, wv_b);
  qkv_gemm_8ph<<<192, 512, 0, stream>>>(hs_b, wq_b, wk_b, wv_b,
                                        bq, bk, bv, q_b, k_b, v_b);
  // X=V, Y=K -> partials hold M^T
  m_partial_kernel<<<dim3(32, 32), 256, 0, stream>>>(v_b, k_b, am, mpart);
  m_reduce_kernel<<<256, 128, 0, stream>>>(mpart, m_b);
  ctx_kernel<<<dim3(32, 16), 256, 0, stream>>>(q_b, m_b, out);
}